// Round 14
// baseline (172.911 us; speedup 1.0000x reference)
//
#include <hip/hip_runtime.h>

// Problem constants (fixed by setup_inputs):
//   x: [B=64, D=64, H=32, W=32] fp32   -> N = B*H*W = 65536 rows of D=64
//   codebook: [K=512, D=64] fp32
// Output layout (all fp32, concatenated flat in return order):
//   [0 .. 4194304)        quant_out [B,D,H,W]
//   [4194304]             loss
//   [4194305]             perplexity
//   [4194306 .. +65536)   encoding_indice [B, H*W] (as float)
//   [4259842 .. +32768)   index_program [B,K]
//   [4292610 .. +32768)   softmax_histogram [B,K]

#define OFF_LOSS 4194304
#define OFF_PERP 4194305
#define OFF_ENC  4194306
#define OFF_IP   4259842
#define OFF_SH   4292610

// Workspace layout (floats). Requires ws_size >= 561729*4 B = 2.25 MB.
//   cbT  [4 segs][16 d][512 codes]  d-seg-major transposed codebook
//   ce2  [512]               ||e_k||^2
//   sh partials [1024][512]  per-block softmax-histogram partial
//   loss partials [1024*4]   per-wave loss partial
//   counter [1] (int)        tail completion counter, zeroed by vq_prep
#define WS_CBT   0
#define WS_CE2   32768
#define WS_SHP   33280
#define WS_LOSS  557568
#define WS_CNT   561664

// R21 (last in-wall move: B-prefetch chain in the 4-reg headroom):
//  - R20 state [measured]: 100us, VALU 44% (~32us irreducible), LDS ~26us,
//    HBM 3.5%: latency-bound at 2 waves/SIMD. Regs 252/256 (acc 128 + arch
//    124). Reads at the 8x16 tile's information minimum (384 b128). Tile
//    alternatives measured worse (R18 126, R15 129, R17 145).
//  - Fix: explicit one-deep B rotation: bq=bqn; bqn=load(next quad); 64
//    FMAs. Every B-read issues ~128 cyc before use (covers ~120-cyc LDS
//    latency). +4 VGPR exactly (124->128); R14 precedent: 128 arch still
//    2 waves/SIMD. dl=15 tail prefetch lands in ce2 region (in-bounds,
//    unused). FMA order/values unchanged -> bit-exact.
//  - Pre-commit: dur>=98 or VGPR>128 or occ~11% -> structural plateau.

typedef float f16v __attribute__((ext_vector_type(16)));

typedef __attribute__((address_space(1))) const void g_void;
typedef __attribute__((address_space(3))) void lds_void;
#define GLOAD_LDS(G, S) \
    __builtin_amdgcn_global_load_lds((g_void*)(G), (lds_void*)(S), 16, 0, 0)

__global__ __launch_bounds__(256) void vq_prep(const float* __restrict__ cb,
                                               float* __restrict__ ws)
{
    if (blockIdx.x == 0 && threadIdx.x == 0)
        ((int*)ws)[WS_CNT] = 0;   // every launch: graph-replay safe

    const int t  = blockIdx.x * 256 + threadIdx.x;   // 0..8191
    const int kg = t >> 4;                           // code 0..511
    const int j  = t & 15;                           // float4 index along D
    const float4 v = ((const float4*)cb)[(kg << 4) + j];
    float pr = v.x * v.x + v.y * v.y + v.z * v.z + v.w * v.w;
    #pragma unroll
    for (int off = 1; off < 16; off <<= 1) pr += __shfl_xor(pr, off, 16);
    if (j == 0) ws[WS_CE2 + kg] = pr;
    // d-seg-major: seg s = d/16 = j>>2; within seg [dl = 4j mod 16][k]
    const int s   = j >> 2;
    const int dl4 = (j & 3) << 2;
    float* base = ws + WS_CBT + (s << 13) + (dl4 << 9) + kg;
    base[0]    = v.x;
    base[512]  = v.y;
    base[1024] = v.z;
    base[1536] = v.w;
}

// ---- macro kit: all acc element indices are integer literals ----
#define FMA4(ACC, AV, K4) \
    ACC[(K4) + 0] = fmaf((AV), bq.x, ACC[(K4) + 0]); \
    ACC[(K4) + 1] = fmaf((AV), bq.y, ACC[(K4) + 1]); \
    ACC[(K4) + 2] = fmaf((AV), bq.z, ACC[(K4) + 2]); \
    ACC[(K4) + 3] = fmaf((AV), bq.w, ACC[(K4) + 3]);

// stage one 32 KB seg (512 codes x 16 d) of cbT into csT via global->LDS DMA
#define STAGE_SEG(S) do { \
    GLOAD_LDS(&cbT4[((S) << 11) + t],        &csT4[t]); \
    GLOAD_LDS(&cbT4[((S) << 11) + 256 + t],  &csT4[256 + t]); \
    GLOAD_LDS(&cbT4[((S) << 11) + 512 + t],  &csT4[512 + t]); \
    GLOAD_LDS(&cbT4[((S) << 11) + 768 + t],  &csT4[768 + t]); \
    GLOAD_LDS(&cbT4[((S) << 11) + 1024 + t], &csT4[1024 + t]); \
    GLOAD_LDS(&cbT4[((S) << 11) + 1280 + t], &csT4[1280 + t]); \
    GLOAD_LDS(&cbT4[((S) << 11) + 1536 + t], &csT4[1536 + t]); \
    GLOAD_LDS(&cbT4[((S) << 11) + 1792 + t], &csT4[1792 + t]); \
} while (0)

// one k-quad's 32-FMA block using the CURRENT bq (quad Q literal)
#define FMA_SET(Q) \
    FMA4(acc0, a0.x, (Q) << 2) \
    FMA4(acc1, a0.y, (Q) << 2) \
    FMA4(acc2, a0.z, (Q) << 2) \
    FMA4(acc3, a0.w, (Q) << 2) \
    FMA4(acc4, a1.x, (Q) << 2) \
    FMA4(acc5, a1.y, (Q) << 2) \
    FMA4(acc6, a1.z, (Q) << 2) \
    FMA4(acc7, a1.w, (Q) << 2)

// 16-d FMA sweep over one seg (full K=512 per d) with a one-deep B
// prefetch rotation: each B-read issues 64 FMAs (~128 cyc) before use.
// Per (row,k): d ascending within seg, segs ascending -> R20's exact chain.
// dl=15's trailing prefetch reads csT+8192.. (ce2 region): in-bounds LDS,
// value never used.
#define GEMM_SEG(S) do { \
    const float* cbb = &csT[tc << 2]; \
    float4 bqn = *(const float4*)cbb; \
    _Pragma("unroll 4") \
    for (int dl = 0; dl < 16; ++dl) { \
        const int d = ((S) << 4) + dl; \
        const float4 a0 = *(const float4*)&xs[(d << 6) + (tr << 3)]; \
        const float4 a1 = *(const float4*)&xs[(d << 6) + (tr << 3) + 4]; \
        float4 bq; \
        bq = bqn; bqn = *(const float4*)(cbb + (dl << 9) + 128); FMA_SET(0); \
        bq = bqn; bqn = *(const float4*)(cbb + (dl << 9) + 256); FMA_SET(1); \
        bq = bqn; bqn = *(const float4*)(cbb + (dl << 9) + 384); FMA_SET(2); \
        bq = bqn; bqn = *(const float4*)(cbb + ((dl + 1) << 9));  FMA_SET(3); \
    } \
} while (0)

#define EPI_C(C, ACC, CE) { \
    const int k = (((C) >> 2) << 7) + (tc << 2) + ((C) & 3); \
    const float t1 = xxr + (CE); \
    const float dist = t1 - 2.f * ACC[C]; \
    ACC[C] = dist; \
    if (dist < m) { m = dist; bk = k; } }

#define EPI_Q(Q, ACC) { \
    const float4 cq = *(const float4*)&ce2[((Q) << 7) + (tc << 2)]; \
    EPI_C(((Q) << 2) + 0, ACC, cq.x) \
    EPI_C(((Q) << 2) + 1, ACC, cq.y) \
    EPI_C(((Q) << 2) + 2, ACC, cq.z) \
    EPI_C(((Q) << 2) + 3, ACC, cq.w) }

#define EXP_C(C, ACC) { \
    const float e = __expf(m - ACC[C]); \
    ACC[C] = e; z += e; }

#define ROW_EPI(I, ACC, INVZ) do { \
    const int row = (tr << 3) + (I); \
    const float xxr = sxx[row]; \
    float m = 1e30f; int bk = 0; \
    EPI_Q(0, ACC)  EPI_Q(1, ACC)  EPI_Q(2, ACC)  EPI_Q(3, ACC) \
    _Pragma("unroll") \
    for (int off = 1; off < 32; off <<= 1) { \
        const float mo = __shfl_xor(m, off, 32); \
        const int   ko = __shfl_xor(bk, off, 32); \
        if (mo < m || (mo == m && ko < bk)) { m = mo; bk = ko; } \
    } \
    float z = 0.f; \
    EXP_C(0, ACC)  EXP_C(1, ACC)  EXP_C(2, ACC)  EXP_C(3, ACC) \
    EXP_C(4, ACC)  EXP_C(5, ACC)  EXP_C(6, ACC)  EXP_C(7, ACC) \
    EXP_C(8, ACC)  EXP_C(9, ACC)  EXP_C(10, ACC) EXP_C(11, ACC) \
    EXP_C(12, ACC) EXP_C(13, ACC) EXP_C(14, ACC) EXP_C(15, ACC) \
    _Pragma("unroll") \
    for (int off = 1; off < 32; off <<= 1) z += __shfl_xor(z, off, 32); \
    INVZ = 1.f / z; \
    if (tc == 0) { \
        sidx[row] = bk; \
        enc[((size_t)b << 10) + row0 + row] = (float)bk; \
    } \
} while (0)

#define HIST_C(C) { \
    const int k = (((C) >> 2) << 7) + (tc << 2) + ((C) & 3); \
    float cs = 0.f; \
    cs += acc0[C] * invz0; cs += acc1[C] * invz1; \
    cs += acc2[C] * invz2; cs += acc3[C] * invz3; \
    cs += acc4[C] * invz4; cs += acc5[C] * invz5; \
    cs += acc6[C] * invz6; cs += acc7[C] * invz7; \
    atomicAdd(&shist[k], cs); }

__global__ __launch_bounds__(256, 1) void vq_main(
    const float* __restrict__ x, const float* __restrict__ cb,
    const float* __restrict__ wsc,   // cbT + ce2 (read-only region)
    float* __restrict__ wso,         // sh + loss partials (write-only region)
    float* __restrict__ out)
{
    __shared__ float  xs[64 * 64];     // xs[d*64 + r], transposed x tile
    __shared__ float  csT[16 * 512];   // [dl][k] for current seg (32 KB)
    __shared__ float  ce2[512];        // ||e_k||^2 (fp32)
    __shared__ float  sxx[64];         // ||x_r||^2 (fp32) per row
    __shared__ int    sidx[64];        // argmin code per row

    const int t    = threadIdx.x;
    const int blk  = blockIdx.x;        // 0..1023
    const int b    = blk >> 4;          // batch index
    const int row0 = (blk & 15) << 6;   // row offset within batch (H*W space)
    const int tr   = t >> 5;            // 0..7  (row group: rows tr*8..tr*8+7)
    const int tc   = t & 31;            // 0..31 (col group)

    const float4* cbT4 = (const float4*)(wsc + WS_CBT);
    float4* csT4 = (float4*)csT;

    // ---- stage x tile via global->LDS DMA (lane-linear: lds = base+lane*16) ----
    {
        const float4* xb4 = (const float4*)(x + ((size_t)b << 16) + row0);
        #pragma unroll
        for (int p = 0; p < 4; ++p) {
            const int fi = (p << 8) + t;      // 0..1023
            const int d  = fi >> 4;
            const int r4 = fi & 15;
            GLOAD_LDS(&xb4[(d << 8) + r4], &xs[(d << 6) + (r4 << 2)]);
        }
    }
    // ---- stage seg 0 (d 0..15, all 512 codes) ----
    STAGE_SEG(0);
    // ---- stage ce2 from ws (plain load/store, drained by the barrier) ----
    if (t < 128) ((float4*)ce2)[t] = ((const float4*)(wsc + WS_CE2))[t];

    __syncthreads();   // drains vmcnt(0): xs + seg 0 + ce2 ready

    // ---- ||x_r||^2 fp32, sequential fmaf over d (bit-exact) ----
    if (t < 64) {
        float s = 0.f;
        for (int d = 0; d < 64; ++d) { const float v = xs[(d << 6) + t]; s = fmaf(v, v, s); }
        sxx[t] = s;
    }

    f16v acc0 = 0.f, acc1 = 0.f, acc2 = 0.f, acc3 = 0.f;
    f16v acc4 = 0.f, acc5 = 0.f, acc6 = 0.f, acc7 = 0.f;

    // ---- GEMM: 4 d-segs, full K per seg (all acc indices literal) ----
    GEMM_SEG(0);
    __syncthreads();   // all waves done reading seg 0
    STAGE_SEG(1);
    __syncthreads();   // vmcnt drained: seg 1 ready (sxx also visible)
    GEMM_SEG(1);
    __syncthreads();
    STAGE_SEG(2);
    __syncthreads();
    GEMM_SEG(2);
    __syncthreads();
    STAGE_SEG(3);
    __syncthreads();
    GEMM_SEG(3);

    // ---- epilogue: ref-exact fp32 dist; per-row argmin + softmax(-dist) ----
    float* enc = out + OFF_ENC;
    float invz0, invz1, invz2, invz3, invz4, invz5, invz6, invz7;
    ROW_EPI(0, acc0, invz0);
    ROW_EPI(1, acc1, invz1);
    ROW_EPI(2, acc2, invz2);
    ROW_EPI(3, acc3, invz3);
    ROW_EPI(4, acc4, invz4);
    ROW_EPI(5, acc5, invz5);
    ROW_EPI(6, acc6, invz6);
    ROW_EPI(7, acc7, invz7);

    __syncthreads();   // all csT reads done; sidx visible

    // ---- softmax histogram: block-reduce in LDS (alias csT), partial to ws ----
    float* shist = csT;
    shist[t] = 0.f; shist[t + 256] = 0.f;
    __syncthreads();
    HIST_C(0)  HIST_C(1)  HIST_C(2)  HIST_C(3)
    HIST_C(4)  HIST_C(5)  HIST_C(6)  HIST_C(7)
    HIST_C(8)  HIST_C(9)  HIST_C(10) HIST_C(11)
    HIST_C(12) HIST_C(13) HIST_C(14) HIST_C(15)
    __syncthreads();
    {
        float* wsh = wso + WS_SHP + ((size_t)blk << 9);
        wsh[t]       = shist[t];
        wsh[t + 256] = shist[t + 256];
    }

    // ---- quantized output + loss partial (from sidx), vectorized ----
    const int r4 = (t & 15) << 2;          // row quad 0..60
    const int dq = t >> 4;                 // 0..15
    const int c0 = sidx[r4], c1 = sidx[r4 + 1], c2 = sidx[r4 + 2], c3 = sidx[r4 + 3];
    float lsum = 0.f;
    #pragma unroll
    for (int p = 0; p < 4; ++p) {
        const int d = (p << 4) + dq;
        float4 q;
        q.x = cb[(c0 << 6) + d];
        q.y = cb[(c1 << 6) + d];
        q.z = cb[(c2 << 6) + d];
        q.w = cb[(c3 << 6) + d];
        const float4 xv = *(const float4*)&xs[(d << 6) + r4];
        const float d0 = q.x - xv.x, d1 = q.y - xv.y, d2 = q.z - xv.z, d3 = q.w - xv.w;
        lsum = fmaf(d0, d0, lsum); lsum = fmaf(d1, d1, lsum);
        lsum = fmaf(d2, d2, lsum); lsum = fmaf(d3, d3, lsum);
        *(float4*)&out[(((size_t)(b << 6) + d) << 10) + row0 + r4] = q;
    }
    #pragma unroll
    for (int off = 1; off < 64; off <<= 1) lsum += __shfl_xor(lsum, off, 64);
    if ((t & 63) == 0) wso[WS_LOSS + (blk << 2) + (t >> 6)] = lsum;
}

// fused vq_reduce + vq_final: 64 blocks; last-block-done (cheap fences:
// each block has only ~4 KB of outstanding stores). Bodies verbatim from
// the R14 kernels -> bit-identical outputs.
__global__ __launch_bounds__(512) void vq_tail(float* __restrict__ ws,
                                               float* __restrict__ out)
{
    __shared__ int hist[512];
    __shared__ int s_last;
    const int b = blockIdx.x, t = threadIdx.x;
    const float* p = ws + WS_SHP + ((size_t)b << 13) + t;   // b*16*512
    float s = 0.f;
    #pragma unroll
    for (int j = 0; j < 16; ++j) s += p[j << 9];
    out[OFF_SH + (b << 9) + t] = s;
    hist[t] = 0;
    __syncthreads();
    const float* enc = out + OFF_ENC + ((size_t)b << 10);
    const int ca  = (int)enc[t];
    const int cbn = (int)enc[t + 512];
    atomicAdd(&hist[ca], 1);
    atomicAdd(&hist[cbn], 1);
    __syncthreads();
    out[OFF_IP + (b << 9) + t] = (float)hist[t];

    __threadfence();   // release this block's ip/sh writes
    if (t == 0) s_last = (atomicAdd(&((int*)ws)[WS_CNT], 1) == 63);
    __syncthreads();
    if (!s_last) return;
    __threadfence();   // acquire other blocks' ip writes

    // ---- vq_final body (verbatim) ----
    __shared__ float red[8], red2[8];
    const float* ip = out + OFF_IP;
    float c0 = 0.f, c1 = 0.f, c2 = 0.f, c3 = 0.f;
    #pragma unroll
    for (int bb = 0; bb < 64; bb += 4) {
        c0 += ip[((bb + 0) << 9) + t];
        c1 += ip[((bb + 1) << 9) + t];
        c2 += ip[((bb + 2) << 9) + t];
        c3 += ip[((bb + 3) << 9) + t];
    }
    const float c = (c0 + c1) + (c2 + c3);
    const float pav = c * (1.0f / 65536.f);
    float h = pav * logf(pav + 1e-10f);
    const float* wl = ws + WS_LOSS;
    float ls = 0.f;
    #pragma unroll
    for (int j = 0; j < 8; ++j) ls += wl[(j << 9) + t];
    #pragma unroll
    for (int off = 1; off < 64; off <<= 1) {
        h  += __shfl_xor(h, off, 64);
        ls += __shfl_xor(ls, off, 64);
    }
    if ((t & 63) == 0) { red[t >> 6] = h; red2[t >> 6] = ls; }
    __syncthreads();
    if (t == 0) {
        float H = 0.f, L = 0.f;
        #pragma unroll
        for (int w = 0; w < 8; ++w) { H += red[w]; L += red2[w]; }
        out[OFF_PERP] = expf(-H);
        out[OFF_LOSS] = L * (1.25f / 4194304.f);
    }
}

extern "C" void kernel_launch(void* const* d_in, const int* in_sizes, int n_in,
                              void* d_out, int out_size, void* d_ws, size_t ws_size,
                              hipStream_t stream)
{
    const float* x  = (const float*)d_in[0];
    const float* cb = (const float*)d_in[1];
    float* out = (float*)d_out;
    float* ws  = (float*)d_ws;
    (void)ws_size;   // requires >= 2.25 MB (561729 floats)

    vq_prep <<<32,   256, 0, stream>>>(cb, ws);
    vq_main <<<1024, 256, 0, stream>>>(x, cb, ws, ws, out);
    vq_tail <<<64,   512, 0, stream>>>(ws, out);
}